// Round 15
// baseline (241.444 us; speedup 1.0000x reference)
//
#include <hip/hip_runtime.h>
#include <hip/hip_bf16.h>

// MimiEuclideanCodebook — SINGLE bf16-MFMA scan (gload_lds staging) with
// packed-u32 top-2 epilogue (one butterfly, no atomics, deterministic) +
// LDS-staged np-bit-exact rescore + fused gather.
// scan: per (row, 128-col tile) store k1,k2 = two smallest packed keys
//   ((fkey(d2a) & ~0x7FF) | code) — u32 min == lex-(value,code) min.
// rescore: gm = min over 16 k1-truncs; thr = gm + DELTA (>= 2*err + trunc).
//   Candidates: tile-top-1 codes with deq1 <= thr (embed rows staged in LDS,
//   np-exact fp32 FMA chains from LDS). Tile rescan iff deq2 <= thr (min2
//   floor-dequant is a valid lower bound); rescan runs dual interleaved
//   chains per lane (ILP 2, loads chain-independent). Lex-(value,idx) min.

typedef float f32x4 __attribute__((ext_vector_type(4)));
typedef short s16x8 __attribute__((ext_vector_type(8)));

#define D_DIM 256
#define N_ROWS 65536
#define K_CODES 2048
#define VQ_EPS 1e-5f
#define DELTA 0.5f

__device__ __forceinline__ short bf16s(float f) {
    __hip_bfloat16 h = __float2bfloat16(f);
    return __builtin_bit_cast(short, h);
}
__device__ __forceinline__ unsigned fkey(float f) {       // order-preserving u32
    unsigned u = __float_as_uint(f);
    return u ^ (unsigned)(((int)u >> 31) | (int)0x80000000);
}
__device__ __forceinline__ float funkey(unsigned k) {
    unsigned u = (k & 0x80000000u) ? (k ^ 0x80000000u) : ~k;
    return __uint_as_float(u);
}
__device__ __forceinline__ void gload16(const void* g, void* l) {
    __builtin_amdgcn_global_load_lds(
        (const __attribute__((address_space(1))) void*)g,
        (__attribute__((address_space(3))) void*)l, 16, 0, 0);
}

// numpy pairwise sum of squares over 256 (verified round 4)
__device__ __forceinline__ void np_sumsq_16lane(const float* a, float* out, int g) {
#pragma clang fp contract(off)
    int j = g & 7, h = g >> 3;
    const float* p = a + h * 128;
    float t = p[j];
    float r = t * t;
#pragma unroll
    for (int i = 1; i < 16; ++i) { float v = p[j + 8 * i]; r += v * v; }
    r += __shfl_xor(r, 1);
    r += __shfl_xor(r, 2);
    r += __shfl_xor(r, 4);
    float other = __shfl_xor(r, 8);
    if (g == 0) *out = r + other;
}

// FUSED codebook prep: embed = es/clip(us) (IEEE div), bf16+swizzle eswz,
// np-pairwise e2 (through LDS; fp32 round-trip is bit-exact). One es read.
__global__ void prep_codebook(const float* __restrict__ es, const float* __restrict__ us,
                              float* __restrict__ embed, unsigned short* __restrict__ eswz,
                              float* __restrict__ e2) {
    __shared__ float le[8][256];
    const int tid = threadIdx.x;
    const int rloc = tid >> 5, idx = tid & 31;            // 8 rows/block, 32 lanes/row
    const int r = blockIdx.x * 8 + rloc;                  // 2048 rows
    const float u = fmaxf(us[r], VQ_EPS);
    f32x4 v0 = *(const f32x4*)&es[r * D_DIM + idx * 8];
    f32x4 v1 = *(const f32x4*)&es[r * D_DIM + idx * 8 + 4];
    f32x4 e0, e1;
#pragma unroll
    for (int j = 0; j < 4; ++j) { e0[j] = v0[j] / u; e1[j] = v1[j] / u; }
    *(f32x4*)&embed[r * D_DIM + idx * 8] = e0;
    *(f32x4*)&embed[r * D_DIM + idx * 8 + 4] = e1;
    *(f32x4*)&le[rloc][idx * 8] = e0;
    *(f32x4*)&le[rloc][idx * 8 + 4] = e1;
    // bf16 + swizzle: this lane's src slot s goes to dst slot s^p (involution)
    int kc = idx >> 2, ss = idx & 3;
    int sd = ss ^ ((r >> 1) & 3);
    s16x8 b;
#pragma unroll
    for (int j = 0; j < 4; ++j) { b[j] = bf16s(e0[j]); b[j + 4] = bf16s(e1[j]); }
    *(s16x8*)&eswz[r * 256 + kc * 32 + sd * 8] = b;
    __syncthreads();
    if (idx < 16) np_sumsq_16lane(&le[rloc][0], &e2[r], idx);
}

// FUSED: x bf16-swizzle + np-pairwise x2 (one HBM pass over x)
__global__ void prep_x(const float* __restrict__ x, unsigned short* __restrict__ dst,
                       float* __restrict__ x2) {
    int gid = blockIdx.x * 256 + threadIdx.x;             // 65536*32
    int r = gid >> 5, idx = gid & 31;
    int kc = idx >> 2, s = idx & 3;
    int k0 = kc * 32 + (s ^ ((r >> 1) & 3)) * 8;
    const float* p = x + r * D_DIM + k0;
    s16x8 v;
#pragma unroll
    for (int j = 0; j < 8; ++j) v[j] = bf16s(p[j]);
    *(s16x8*)&dst[r * 256 + kc * 32 + s * 8] = v;
    if (idx < 16)                                         // L1-hot re-read
        np_sumsq_16lane(x + r * D_DIM, x2 + r, idx);
}

// ---- single bf16 MFMA scan: per-(row,tile) packed top-2, no atomics ----------
__launch_bounds__(256, 2)
__global__ void vq_scan(const unsigned short* __restrict__ xswz,
                        const unsigned short* __restrict__ eswz,
                        const float* __restrict__ e2, const float* __restrict__ x2,
                        unsigned* __restrict__ keys1, unsigned* __restrict__ keys2) {
    __shared__ __align__(16) short lds[2][2][4096];       // [buf][A/B][8KB]

    const int bid = blockIdx.x;
    const int swz = (bid & 7) * 1024 + (bid >> 3);        // XCD-contiguous tiles
    const int mt = swz >> 4, nt = swz & 15;
    const int m_base = mt * 128, n_base = nt * 128;
    const int tid = threadIdx.x, lane = tid & 63, wid = tid >> 6;
    const int rb = wid * 32;                              // wave: rows rb..rb+31
    const int l15 = lane & 15, lg = lane >> 4;

    f32x4 acc[2][8];
#pragma unroll
    for (int m = 0; m < 2; ++m)
#pragma unroll
        for (int n = 0; n < 8; ++n) { f32x4 z = {0.f, 0.f, 0.f, 0.f}; acc[m][n] = z; }

    auto stage = [&](int buf, int kc) {
#pragma unroll
        for (int i = 0; i < 2; ++i) {
            int off = i * 4096 + wid * 1024 + lane * 16;  // linear LDS dest bytes
            int row = off >> 6, slot = (off >> 4) & 3;    // pre-permuted source
            gload16((const char*)xswz + (((size_t)(m_base + row)) << 9) + (kc << 6) + (slot << 4),
                    (char*)&lds[buf][0][0] + off);
            gload16((const char*)eswz + (((size_t)(n_base + row)) << 9) + (kc << 6) + (slot << 4),
                    (char*)&lds[buf][1][0] + off);
        }
    };
    auto compute = [&](int buf) {
        const short* A = &lds[buf][0][0];
        const short* B = &lds[buf][1][0];
        s16x8 af[2], bf[8];
#pragma unroll
        for (int m = 0; m < 2; ++m) {
            int R = rb + m * 16 + l15, s = lg ^ ((R >> 1) & 3);
            af[m] = *(const s16x8*)&A[R * 32 + s * 8];
        }
#pragma unroll
        for (int n = 0; n < 8; ++n) {
            int R = n * 16 + l15, s = lg ^ ((R >> 1) & 3);
            bf[n] = *(const s16x8*)&B[R * 32 + s * 8];
        }
#pragma unroll
        for (int m = 0; m < 2; ++m)
#pragma unroll
            for (int n = 0; n < 8; ++n)
                acc[m][n] = __builtin_amdgcn_mfma_f32_16x16x32_bf16(af[m], bf[n], acc[m][n], 0, 0, 0);
    };

    stage(0, 0);
    __syncthreads();
#pragma unroll 1
    for (int kc = 0; kc < 8; ++kc) {
        if (kc < 7) stage((kc + 1) & 1, kc + 1);          // loads fly under compute
        compute(kc & 1);
        __syncthreads();                                  // drain gload + readers done
    }

    // epilogue: pack d2a into lex keys; per-lane top-2 (3 min/max per value);
    // ONE 4-step pair-merge butterfly over 16 lanes. No dynamic reg indexing.
    // C/D layout (rounds 8/10 verified): col = n*16 + l15, row = lg*4+j (+m*16)
    const int grow0 = m_base + rb + lg * 4;
    float e2v[8];
#pragma unroll
    for (int n = 0; n < 8; ++n) e2v[n] = e2[n_base + n * 16 + l15];

#pragma unroll
    for (int m = 0; m < 2; ++m) {
#pragma unroll
        for (int j = 0; j < 4; ++j) {
            int gr = grow0 + m * 16 + j;
            float x2v = x2[gr];
            unsigned k1 = 0xFFFFFFFFu, k2 = 0xFFFFFFFFu;
#pragma unroll
            for (int n = 0; n < 8; ++n) {
                float d2 = (x2v - 2.0f * acc[m][n][j]) + e2v[n];
                unsigned pk = (fkey(d2) & 0xFFFFF800u)
                              | (unsigned)(n_base + n * 16 + l15);
                unsigned lo = pk < k1 ? pk : k1;
                unsigned hi = pk < k1 ? k1 : pk;
                k2 = hi < k2 ? hi : k2;
                k1 = lo;
            }
#pragma unroll
            for (int s = 1; s < 16; s <<= 1) {            // bitonic pair-merge
                unsigned o1 = __shfl_xor(k1, s);
                unsigned o2 = __shfl_xor(k2, s);
                unsigned lo = o1 < k1 ? o1 : k1;
                unsigned hi = o1 < k1 ? k1 : o1;
                unsigned m2 = o2 < k2 ? o2 : k2;
                k2 = hi < m2 ? hi : m2;
                k1 = lo;
            }
            if (l15 == 0) {
                keys1[gr * 16 + nt] = k1;
                keys2[gr * 16 + nt] = k2;
            }
        }
    }
}

// ------- LDS-staged np-exact rescore (wave per row) + fused gather ------------
__launch_bounds__(256, 4)
__global__ void vq_rescore(const float* __restrict__ x, const float* __restrict__ embed,
                           const float* __restrict__ e2, const float* __restrict__ x2,
                           const unsigned* __restrict__ keys1,
                           const unsigned* __restrict__ keys2,
                           const float* __restrict__ es, const float* __restrict__ us,
                           float* __restrict__ out) {
    __shared__ float lx[4][256];                          // x rows (exact fp32)
    __shared__ float le[4][4][260];                       // 4 staged embed rows/wave
    __shared__ int lcode[4][16];
    __shared__ int lnc[4];

    const int tid = threadIdx.x, w = tid >> 6, lane = tid & 63;
    const int r = blockIdx.x * 4 + w;
    const int t16 = lane & 15;
    const float x2v = x2[r];

    // stage x row (coalesced 1KB; LDS round-trip is bit-exact)
    *(f32x4*)&lx[w][lane * 4] = *(const f32x4*)&x[r * D_DIM + lane * 4];

    unsigned key = keys1[r * 16 + t16];
    unsigned kd = key & 0xFFFFF800u;                      // truncated value key
    unsigned kmin = kd;
#pragma unroll
    for (int s = 1; s < 16; s <<= 1) {                    // gm over 16 tiles
        unsigned ok = __shfl_xor(kmin, s);
        kmin = ok < kmin ? ok : kmin;
    }
    const float thr = funkey(kmin) + DELTA;
    const float deq = funkey(kd);                         // floor of tile min1

    bool cand = (lane < 16) && (deq <= thr);
    bool resc = (lane < 16) &&
                (funkey(keys2[r * 16 + t16] & 0xFFFFF800u) <= thr);
    unsigned long long cmask = __ballot(cand);
    unsigned long long rmask = __ballot(resc);            // bits 0..15 = tiles
    if (cand)
        lcode[w][__popcll(cmask & ((1ull << lane) - 1ull))] = (int)(key & 0x7FFu);
    if (lane == 0) lnc[w] = __popcll(cmask);
    __syncthreads();                                      // lx, lcode, lnc visible

    int gmax = lnc[0];
#pragma unroll
    for (int i = 1; i < 4; ++i) gmax = max(gmax, lnc[i]);
    gmax = (gmax + 3) >> 2;                               // block-uniform groups

    float bv = __builtin_inff();
    int bi = 0x7FFFFFFF;
    auto lexmin = [&](float d2, int code) {
        if (d2 < bv || (d2 == bv && code < bi)) { bv = d2; bi = code; }
    };

#pragma unroll 1
    for (int g = 0; g < gmax; ++g) {
        const int nc = lnc[w];                            // wave-uniform
#pragma unroll
        for (int v = 0; v < 4; ++v) {                     // stage <=4 embed rows
            int idx = g * 4 + v;
            if (idx < nc) {
                int code = lcode[w][idx];
                *(f32x4*)&le[w][v][lane * 4] =
                    *(const f32x4*)&embed[code * D_DIM + lane * 4];
            }
        }
        __syncthreads();
        int idx = g * 4 + lane;                           // lanes 0..3 run chains
        if (lane < 4 && idx < nc) {
            int code = lcode[w][idx];
            float t = 0.0f;
#pragma unroll 8
            for (int k4 = 0; k4 < 64; ++k4) {             // single chain, k ascending
                f32x4 a4 = *(const f32x4*)&lx[w][k4 * 4];     // broadcast
                f32x4 e4 = *(const f32x4*)&le[w][lane][k4 * 4];
                t = __builtin_fmaf(a4[0], e4[0], t);
                t = __builtin_fmaf(a4[1], e4[1], t);
                t = __builtin_fmaf(a4[2], e4[2], t);
                t = __builtin_fmaf(a4[3], e4[3], t);
            }
            lexmin((x2v - 2.0f * t) + e2[code], code);    // np op order
        }
        __syncthreads();                                  // before le overwrite
    }

    // tiles whose min2 lower-bound clears thr -> exact rescan: 2 codes/lane as
    // DUAL interleaved chains (each single-accumulator, ascending k; ILP 2)
    while (rmask) {
        int t2 = __ffsll(rmask) - 1;
        rmask &= rmask - 1;
        int ca = t2 * 128 + lane, cb = ca + 64;
        float ta = 0.0f, tb = 0.0f;
#pragma unroll 8
        for (int k4 = 0; k4 < 64; ++k4) {
            f32x4 a4 = *(const f32x4*)&lx[w][k4 * 4];
            f32x4 ea = *(const f32x4*)&embed[ca * D_DIM + k4 * 4];
            f32x4 eb = *(const f32x4*)&embed[cb * D_DIM + k4 * 4];
            ta = __builtin_fmaf(a4[0], ea[0], ta);
            tb = __builtin_fmaf(a4[0], eb[0], tb);
            ta = __builtin_fmaf(a4[1], ea[1], ta);
            tb = __builtin_fmaf(a4[1], eb[1], tb);
            ta = __builtin_fmaf(a4[2], ea[2], ta);
            tb = __builtin_fmaf(a4[2], eb[2], tb);
            ta = __builtin_fmaf(a4[3], ea[3], ta);
            tb = __builtin_fmaf(a4[3], eb[3], tb);
        }
        lexmin((x2v - 2.0f * ta) + e2[ca], ca);
        lexmin((x2v - 2.0f * tb) + e2[cb], cb);
    }

#pragma unroll
    for (int s = 1; s < 64; s <<= 1) {                    // 64-lane lex allreduce
        float ov = __shfl_xor(bv, s);
        int oi = __shfl_xor(bi, s);
        if (ov < bv || (ov == bv && oi < bi)) { bv = ov; bi = oi; }
    }
    if (lane == 0) out[r] = (float)bi;

    // fused gather: quantized[r] = es[bi]/max(us[bi],eps); 64 lanes x 4 floats
    float u = fmaxf(us[bi], VQ_EPS);
    f32x4 wv = *(const f32x4*)&es[bi * D_DIM + lane * 4];
    f32x4 o;
#pragma unroll
    for (int j = 0; j < 4; ++j) o[j] = wv[j] / u;         // IEEE div == np bitwise
    *(f32x4*)&out[N_ROWS + r * D_DIM + lane * 4] = o;
}

extern "C" void kernel_launch(void* const* d_in, const int* in_sizes, int n_in,
                              void* d_out, int out_size, void* d_ws, size_t ws_size,
                              hipStream_t stream) {
    const float* x = (const float*)d_in[0];               // [65536, 256]
    const float* es = (const float*)d_in[1];              // [2048, 256]
    const float* us = (const float*)d_in[2];              // [2048]
    float* out = (float*)d_out;

    char* w = (char*)d_ws;                                // total 45,359,104 B
    unsigned short* xswz = (unsigned short*)(w);                  // 33,554,432
    unsigned short* eswz = (unsigned short*)(w + 33554432);       //  1,048,576
    float* embed         = (float*)(w + 34603008);                //  2,097,152
    float* e2            = (float*)(w + 36700160);                //      8,192
    float* x2            = (float*)(w + 36708352);                //    262,144
    unsigned* keys1      = (unsigned*)(w + 36970496);             //  4,194,304
    unsigned* keys2      = (unsigned*)(w + 41164800);             //  4,194,304

    hipLaunchKernelGGL(prep_codebook, dim3(256), dim3(256), 0, stream,
                       es, us, embed, eswz, e2);
    hipLaunchKernelGGL(prep_x, dim3(8192), dim3(256), 0, stream, x, xswz, x2);
    hipLaunchKernelGGL(vq_scan, dim3(8192), dim3(256), 0, stream,
                       xswz, eswz, e2, x2, keys1, keys2);
    hipLaunchKernelGGL(vq_rescore, dim3(16384), dim3(256), 0, stream,
                       x, embed, e2, x2, keys1, keys2, es, us, out);
}

// Round 16
// 229.340 us; speedup vs baseline: 1.0528x; 1.0528x over previous
//
#include <hip/hip_runtime.h>
#include <hip/hip_bf16.h>

// MimiEuclideanCodebook — SINGLE fp16-MFMA scan (gload_lds staging) with
// per-tile TOP-4 packed-key epilogue (no atomics, deterministic) +
// barrier-free LDS-staged np-bit-exact rescore + fused gather.
// scan: per (row, 128-col tile) store uint4 = four smallest packed keys
//   ((fkey(d2a) & ~0x7FF) | code); u32 sort == lex-(value,code) sort.
// fp16 halves the scan error 4x vs bf16 -> DELTA=0.25 with >=10-sigma margin
//   (near-min codes have |e| <= ~6.5 -> sigma_d2a <= 0.013; margin after
//   0.0625 trunc slack = 0.1875).
// rescore: thr = gm_trunc + DELTA. Candidates = stored codes with deq <= thr
//   (floor-dequant <= actual => never drops j*). Tile rescan iff deq4 <= thr
//   (>=4 codes within thr in one tile; P ~ 0.4%). np-exact fp32 FMA chains
//   from LDS; lex-(value,idx) min => np argmin (first-min ties).

typedef float f32x4 __attribute__((ext_vector_type(4)));
typedef short s16x8 __attribute__((ext_vector_type(8)));
typedef _Float16 h16x8 __attribute__((ext_vector_type(8)));

#define D_DIM 256
#define N_ROWS 65536
#define K_CODES 2048
#define VQ_EPS 1e-5f
#define DELTA 0.25f

__device__ __forceinline__ short f16s(float f) {
    _Float16 h = (_Float16)f;                             // RTN
    return __builtin_bit_cast(short, h);
}
__device__ __forceinline__ unsigned fkey(float f) {       // order-preserving u32
    unsigned u = __float_as_uint(f);
    return u ^ (unsigned)(((int)u >> 31) | (int)0x80000000);
}
__device__ __forceinline__ float funkey(unsigned k) {
    unsigned u = (k & 0x80000000u) ? (k ^ 0x80000000u) : ~k;
    return __uint_as_float(u);
}
__device__ __forceinline__ void gload16(const void* g, void* l) {
    __builtin_amdgcn_global_load_lds(
        (const __attribute__((address_space(1))) void*)g,
        (__attribute__((address_space(3))) void*)l, 16, 0, 0);
}

// numpy pairwise sum of squares over 256 (verified round 4)
__device__ __forceinline__ void np_sumsq_16lane(const float* a, float* out, int g) {
#pragma clang fp contract(off)
    int j = g & 7, h = g >> 3;
    const float* p = a + h * 128;
    float t = p[j];
    float r = t * t;
#pragma unroll
    for (int i = 1; i < 16; ++i) { float v = p[j + 8 * i]; r += v * v; }
    r += __shfl_xor(r, 1);
    r += __shfl_xor(r, 2);
    r += __shfl_xor(r, 4);
    float other = __shfl_xor(r, 8);
    if (g == 0) *out = r + other;
}

// FUSED codebook prep: embed = es/clip(us) (IEEE div), fp16+swizzle eswz,
// np-pairwise e2 (through LDS; fp32 round-trip is bit-exact). One es read.
__global__ void prep_codebook(const float* __restrict__ es, const float* __restrict__ us,
                              float* __restrict__ embed, unsigned short* __restrict__ eswz,
                              float* __restrict__ e2) {
    __shared__ float le[8][256];
    const int tid = threadIdx.x;
    const int rloc = tid >> 5, idx = tid & 31;            // 8 rows/block, 32 lanes/row
    const int r = blockIdx.x * 8 + rloc;                  // 2048 rows
    const float u = fmaxf(us[r], VQ_EPS);
    f32x4 v0 = *(const f32x4*)&es[r * D_DIM + idx * 8];
    f32x4 v1 = *(const f32x4*)&es[r * D_DIM + idx * 8 + 4];
    f32x4 e0, e1;
#pragma unroll
    for (int j = 0; j < 4; ++j) { e0[j] = v0[j] / u; e1[j] = v1[j] / u; }
    *(f32x4*)&embed[r * D_DIM + idx * 8] = e0;
    *(f32x4*)&embed[r * D_DIM + idx * 8 + 4] = e1;
    *(f32x4*)&le[rloc][idx * 8] = e0;
    *(f32x4*)&le[rloc][idx * 8 + 4] = e1;
    int kc = idx >> 2, ss = idx & 3;
    int sd = ss ^ ((r >> 1) & 3);                         // swizzle involution
    s16x8 b;
#pragma unroll
    for (int j = 0; j < 4; ++j) { b[j] = f16s(e0[j]); b[j + 4] = f16s(e1[j]); }
    *(s16x8*)&eswz[r * 256 + kc * 32 + sd * 8] = b;
    __syncthreads();
    if (idx < 16) np_sumsq_16lane(&le[rloc][0], &e2[r], idx);
}

// FUSED: x fp16-swizzle + np-pairwise x2 (one HBM pass over x)
__global__ void prep_x(const float* __restrict__ x, unsigned short* __restrict__ dst,
                       float* __restrict__ x2) {
    int gid = blockIdx.x * 256 + threadIdx.x;             // 65536*32
    int r = gid >> 5, idx = gid & 31;
    int kc = idx >> 2, s = idx & 3;
    int k0 = kc * 32 + (s ^ ((r >> 1) & 3)) * 8;
    const float* p = x + r * D_DIM + k0;
    s16x8 v;
#pragma unroll
    for (int j = 0; j < 8; ++j) v[j] = f16s(p[j]);
    *(s16x8*)&dst[r * 256 + kc * 32 + s * 8] = v;
    if (idx < 16)                                         // L1-hot re-read
        np_sumsq_16lane(x + r * D_DIM, x2 + r, idx);
}

// ---- single fp16 MFMA scan: per-(row,tile) sorted top-4, no atomics ----------
__launch_bounds__(256, 2)
__global__ void vq_scan(const unsigned short* __restrict__ xswz,
                        const unsigned short* __restrict__ eswz,
                        const float* __restrict__ e2, const float* __restrict__ x2,
                        uint4* __restrict__ keys) {
    __shared__ __align__(16) short lds[2][2][4096];       // [buf][A/B][8KB]

    const int bid = blockIdx.x;
    const int swz = (bid & 7) * 1024 + (bid >> 3);        // XCD-contiguous tiles
    const int mt = swz >> 4, nt = swz & 15;
    const int m_base = mt * 128, n_base = nt * 128;
    const int tid = threadIdx.x, lane = tid & 63, wid = tid >> 6;
    const int rb = wid * 32;                              // wave: rows rb..rb+31
    const int l15 = lane & 15, lg = lane >> 4;

    f32x4 acc[2][8];
#pragma unroll
    for (int m = 0; m < 2; ++m)
#pragma unroll
        for (int n = 0; n < 8; ++n) { f32x4 z = {0.f, 0.f, 0.f, 0.f}; acc[m][n] = z; }

    auto stage = [&](int buf, int kc) {
#pragma unroll
        for (int i = 0; i < 2; ++i) {
            int off = i * 4096 + wid * 1024 + lane * 16;  // linear LDS dest bytes
            int row = off >> 6, slot = (off >> 4) & 3;    // pre-permuted source
            gload16((const char*)xswz + (((size_t)(m_base + row)) << 9) + (kc << 6) + (slot << 4),
                    (char*)&lds[buf][0][0] + off);
            gload16((const char*)eswz + (((size_t)(n_base + row)) << 9) + (kc << 6) + (slot << 4),
                    (char*)&lds[buf][1][0] + off);
        }
    };
    auto compute = [&](int buf) {
        const short* A = &lds[buf][0][0];
        const short* B = &lds[buf][1][0];
        h16x8 af[2], bf[8];
#pragma unroll
        for (int m = 0; m < 2; ++m) {
            int R = rb + m * 16 + l15, s = lg ^ ((R >> 1) & 3);
            af[m] = __builtin_bit_cast(h16x8, *(const s16x8*)&A[R * 32 + s * 8]);
        }
#pragma unroll
        for (int n = 0; n < 8; ++n) {
            int R = n * 16 + l15, s = lg ^ ((R >> 1) & 3);
            bf[n] = __builtin_bit_cast(h16x8, *(const s16x8*)&B[R * 32 + s * 8]);
        }
#pragma unroll
        for (int m = 0; m < 2; ++m)
#pragma unroll
            for (int n = 0; n < 8; ++n)
                acc[m][n] = __builtin_amdgcn_mfma_f32_16x16x32_f16(af[m], bf[n], acc[m][n], 0, 0, 0);
    };

    stage(0, 0);
    __syncthreads();
#pragma unroll 1
    for (int kc = 0; kc < 8; ++kc) {
        if (kc < 7) stage((kc + 1) & 1, kc + 1);          // loads fly under compute
        compute(kc & 1);
        __syncthreads();                                  // drain gload + readers done
    }

    // epilogue: packed keys; per-lane sorted top-4 insert (7 ops/value);
    // 4-step bitonic pair-merge butterfly over 16 lanes (4 shfl + 12 ops/step).
    // C/D layout (rounds 8/10 verified): col = n*16 + l15, row = lg*4+j (+m*16)
    const int grow0 = m_base + rb + lg * 4;
    float e2v[8];
#pragma unroll
    for (int n = 0; n < 8; ++n) e2v[n] = e2[n_base + n * 16 + l15];

#pragma unroll
    for (int m = 0; m < 2; ++m) {
#pragma unroll
        for (int j = 0; j < 4; ++j) {
            int gr = grow0 + m * 16 + j;
            float x2v = x2[gr];
            unsigned k1 = 0xFFFFFFFFu, k2 = 0xFFFFFFFFu;
            unsigned k3 = 0xFFFFFFFFu, k4 = 0xFFFFFFFFu;
#pragma unroll
            for (int n = 0; n < 8; ++n) {
                float d2 = (x2v - 2.0f * acc[m][n][j]) + e2v[n];
                unsigned pk = (fkey(d2) & 0xFFFFF800u)
                              | (unsigned)(n_base + n * 16 + l15);
                unsigned a = min(pk, k1), b = max(pk, k1); k1 = a;   // sorted insert
                a = min(b, k2); b = max(b, k2); k2 = a;
                a = min(b, k3); b = max(b, k3); k3 = a;
                k4 = min(b, k4);
            }
#pragma unroll
            for (int s = 1; s < 16; s <<= 1) {            // bitonic 4-merge
                unsigned o1 = __shfl_xor(k1, s), o2 = __shfl_xor(k2, s);
                unsigned o3 = __shfl_xor(k3, s), o4 = __shfl_xor(k4, s);
                unsigned c1 = min(k1, o4), c2 = min(k2, o3);
                unsigned c3 = min(k3, o2), c4 = min(k4, o1);
                unsigned t;
                t = min(c1, c3); c3 = max(c1, c3); c1 = t;
                t = min(c2, c4); c4 = max(c2, c4); c2 = t;
                t = min(c1, c2); c2 = max(c1, c2); c1 = t;
                t = min(c3, c4); c4 = max(c3, c4); c3 = t;
                k1 = c1; k2 = c2; k3 = c3; k4 = c4;
            }
            if (l15 == 0) {
                uint4 kq; kq.x = k1; kq.y = k2; kq.z = k3; kq.w = k4;
                keys[gr * 16 + nt] = kq;
            }
        }
    }
}

// -- barrier-free LDS-staged np-exact rescore (wave per row) + fused gather ----
__launch_bounds__(256, 4)
__global__ void vq_rescore(const float* __restrict__ x, const float* __restrict__ embed,
                           const float* __restrict__ e2, const float* __restrict__ x2,
                           const uint4* __restrict__ keys,
                           const float* __restrict__ es, const float* __restrict__ us,
                           float* __restrict__ out) {
    __shared__ float lx[4][256];                          // per-wave x row
    __shared__ float le[4][8][260];                       // per-wave staged embeds
    __shared__ int lcode[4][64];                          // per-wave cand codes

    const int tid = threadIdx.x, w = tid >> 6, lane = tid & 63;
    const int r = blockIdx.x * 4 + w;
    const int t16 = lane & 15;
    const float x2v = x2[r];
    const unsigned long long lt = (1ull << lane) - 1ull;

    // stage x row (wave-private; wave-lockstep + in-order LDS => no barrier)
    *(f32x4*)&lx[w][lane * 4] = *(const f32x4*)&x[r * D_DIM + lane * 4];

    uint4 kq = keys[r * 16 + t16];                        // 4 copies per 16-group
    unsigned kmin = kq.x & 0xFFFFF800u;
#pragma unroll
    for (int s = 1; s < 16; s <<= 1) {                    // gm over 16 tiles
        unsigned ok = __shfl_xor(kmin, s);
        kmin = ok < kmin ? ok : kmin;
    }
    const float thr = funkey(kmin) + DELTA;

    // compact candidates (slot-major, deterministic ballot order)
    unsigned sv[4] = {kq.x, kq.y, kq.z, kq.w};
    int nc = 0;
#pragma unroll
    for (int s = 0; s < 4; ++s) {                         // static after unroll
        bool v = (lane < 16) && (funkey(sv[s] & 0xFFFFF800u) <= thr);
        unsigned long long b = __ballot(v);
        if (v) lcode[w][nc + __popcll(b & lt)] = (int)(sv[s] & 0x7FFu);
        nc += (int)__popcll(b);
    }
    bool resc = (lane < 16) && (funkey(kq.w & 0xFFFFF800u) <= thr);
    unsigned long long rmask = __ballot(resc);            // bits 0..15 = tiles

    float bv = __builtin_inff();
    int bi = 0x7FFFFFFF;
    auto lexmin = [&](float d2, int code) {
        if (d2 < bv || (d2 == bv && code < bi)) { bv = d2; bi = code; }
    };

#pragma unroll 1
    for (int g = 0; g < (nc + 7) >> 3; ++g) {             // wave-uniform nc
#pragma unroll
        for (int v = 0; v < 8; ++v) {                     // stage <=8 embed rows
            int idx = g * 8 + v;
            if (idx < nc) {
                int code = lcode[w][idx];
                *(f32x4*)&le[w][v][lane * 4] =
                    *(const f32x4*)&embed[code * D_DIM + lane * 4];
            }
        }
        int idx = g * 8 + lane;                           // lanes 0..7 run chains
        if (lane < 8 && idx < nc) {
            int code = lcode[w][idx];
            float t = 0.0f;
#pragma unroll 8
            for (int k4 = 0; k4 < 64; ++k4) {             // single chain, k ascending
                f32x4 a4 = *(const f32x4*)&lx[w][k4 * 4];     // broadcast
                f32x4 e4 = *(const f32x4*)&le[w][lane][k4 * 4];
                t = __builtin_fmaf(a4[0], e4[0], t);
                t = __builtin_fmaf(a4[1], e4[1], t);
                t = __builtin_fmaf(a4[2], e4[2], t);
                t = __builtin_fmaf(a4[3], e4[3], t);
            }
            lexmin((x2v - 2.0f * t) + e2[code], code);    // np op order
        }
    }

    // rare (~0.4%): >=4 codes within thr in one tile -> exact rescan of tile
    while (rmask) {
        int t2 = __ffsll(rmask) - 1;
        rmask &= rmask - 1;
        int ca = t2 * 128 + lane, cb = ca + 64;
        float ta = 0.0f, tb = 0.0f;
#pragma unroll 8
        for (int k4 = 0; k4 < 64; ++k4) {                 // dual interleaved chains
            f32x4 a4 = *(const f32x4*)&lx[w][k4 * 4];
            f32x4 ea = *(const f32x4*)&embed[ca * D_DIM + k4 * 4];
            f32x4 eb = *(const f32x4*)&embed[cb * D_DIM + k4 * 4];
            ta = __builtin_fmaf(a4[0], ea[0], ta);
            tb = __builtin_fmaf(a4[0], eb[0], tb);
            ta = __builtin_fmaf(a4[1], ea[1], ta);
            tb = __builtin_fmaf(a4[1], eb[1], tb);
            ta = __builtin_fmaf(a4[2], ea[2], ta);
            tb = __builtin_fmaf(a4[2], eb[2], tb);
            ta = __builtin_fmaf(a4[3], ea[3], ta);
            tb = __builtin_fmaf(a4[3], eb[3], tb);
        }
        lexmin((x2v - 2.0f * ta) + e2[ca], ca);
        lexmin((x2v - 2.0f * tb) + e2[cb], cb);
    }

#pragma unroll
    for (int s = 1; s < 64; s <<= 1) {                    // 64-lane lex allreduce
        float ov = __shfl_xor(bv, s);
        int oi = __shfl_xor(bi, s);
        if (ov < bv || (ov == bv && oi < bi)) { bv = ov; bi = oi; }
    }
    if (lane == 0) out[r] = (float)bi;

    // fused gather: quantized[r] = es[bi]/max(us[bi],eps); 64 lanes x 4 floats
    float u = fmaxf(us[bi], VQ_EPS);
    f32x4 wv = *(const f32x4*)&es[bi * D_DIM + lane * 4];
    f32x4 o;
#pragma unroll
    for (int j = 0; j < 4; ++j) o[j] = wv[j] / u;         // IEEE div == np bitwise
    *(f32x4*)&out[N_ROWS + r * D_DIM + lane * 4] = o;
}

extern "C" void kernel_launch(void* const* d_in, const int* in_sizes, int n_in,
                              void* d_out, int out_size, void* d_ws, size_t ws_size,
                              hipStream_t stream) {
    const float* x = (const float*)d_in[0];               // [65536, 256]
    const float* es = (const float*)d_in[1];              // [2048, 256]
    const float* us = (const float*)d_in[2];              // [2048]
    float* out = (float*)d_out;

    char* w = (char*)d_ws;                                // total 53,747,712 B
    unsigned short* xswz = (unsigned short*)(w);                  // 33,554,432
    unsigned short* eswz = (unsigned short*)(w + 33554432);       //  1,048,576
    float* embed         = (float*)(w + 34603008);                //  2,097,152
    float* e2            = (float*)(w + 36700160);                //      8,192
    float* x2            = (float*)(w + 36708352);                //    262,144
    uint4* keys          = (uint4*)(w + 36970496);                // 16,777,216

    hipLaunchKernelGGL(prep_codebook, dim3(256), dim3(256), 0, stream,
                       es, us, embed, eswz, e2);
    hipLaunchKernelGGL(prep_x, dim3(8192), dim3(256), 0, stream, x, xswz, x2);
    hipLaunchKernelGGL(vq_scan, dim3(8192), dim3(256), 0, stream,
                       xswz, eswz, e2, x2, keys);
    hipLaunchKernelGGL(vq_rescore, dim3(16384), dim3(256), 0, stream,
                       x, embed, e2, x2, keys, es, us, out);
}